// Round 8
// baseline (209.465 us; speedup 1.0000x reference)
//
#include <hip/hip_runtime.h>

#define FR   8000
#define FRP  8192    // padded to 64*128 for XCD-chunked dist mapping
#define DD   512
#define CK   1024
#define KSZ  320
#define TT   500
#define NB   16

typedef unsigned int u32;
typedef unsigned short u16;
typedef __attribute__((ext_vector_type(8))) short b8;   // 8 x bf16 bits
typedef __attribute__((ext_vector_type(4))) float f4;

__device__ __forceinline__ float bf2f(u16 h) {
    u32 u = ((u32)h) << 16;
    return __builtin_bit_cast(float, u);
}
__device__ __forceinline__ u16 f2bf(float f) {  // RNE
    u32 u = __builtin_bit_cast(u32, f);
    u32 r = u + 0x7FFFu + ((u >> 16) & 1u);
    return (u16)(r >> 16);
}

__device__ __forceinline__ void gld16(const u16* g, u16* s) {
    __builtin_amdgcn_global_load_lds(
        (const __attribute__((address_space(1))) u32*)g,
        (__attribute__((address_space(3))) u32*)s, 16, 0, 0);
}

__device__ __forceinline__ f4 mfma(b8 a, b8 b, f4 c) {
    return __builtin_amdgcn_mfma_f32_16x16x32_bf16(a, b, c, 0, 0, 0);
}

__device__ __forceinline__ void split8(float4 a, float4 b, u16* dh, u16* dl) {
    float xs[8] = {a.x, a.y, a.z, a.w, b.x, b.y, b.z, b.w};
    union { u16 u[8]; b8 v; } H, L;
#pragma unroll
    for (int i = 0; i < 8; ++i) {
        u16 h = f2bf(xs[i]);
        H.u[i] = h;
        L.u[i] = f2bf(xs[i] - bf2f(h));
    }
    *(b8*)dh = H.v;
    *(b8*)dl = L.v;
}

// ---------------------------------------------------------------------------
// Merged prep:
//  [0,80)      split enc_w
//  [80,336)    split cb
//  [336,368)   cbnorm
//  [368,1618)  split wav
//  [1618,1666) dwf transpose: dwf[s][d] = dec_w[d][319-s], rows 320..383 zero
//  [1666]      zero tavg accumulator (for k_enc atomics)
// ---------------------------------------------------------------------------
__global__ __launch_bounds__(256) void k_prep(const float* __restrict__ enc_w,
                                              u16* __restrict__ ewh, u16* __restrict__ ewl,
                                              const float* __restrict__ cb,
                                              u16* __restrict__ cbh, u16* __restrict__ cbl,
                                              const float* __restrict__ dw,
                                              u16* __restrict__ dwfh, u16* __restrict__ dwfl,
                                              float* __restrict__ cbn,
                                              const float* __restrict__ wav,
                                              u16* __restrict__ wavh, u16* __restrict__ wavl,
                                              float* __restrict__ tsum) {
    const int bid = blockIdx.x, tid = threadIdx.x;
    if (bid < 80) {
        int i = (bid * 256 + tid) * 8;
        float4 a = *(const float4*)&enc_w[i];
        float4 b = *(const float4*)&enc_w[i + 4];
        split8(a, b, &ewh[i], &ewl[i]);
    } else if (bid < 336) {
        int i = ((bid - 80) * 256 + tid) * 8;
        float4 a = *(const float4*)&cb[i];
        float4 b = *(const float4*)&cb[i + 4];
        split8(a, b, &cbh[i], &cbl[i]);
    } else if (bid < 368) {
        int c = (bid - 336) * 32 + (tid >> 3);
        int l = tid & 7;
        float s = 0.f;
        for (int j = l * 4; j < DD; j += 32) {
            float4 v = *(const float4*)&cb[c * DD + j];
            s += v.x * v.x + v.y * v.y + v.z * v.z + v.w * v.w;
        }
        s += __shfl_xor(s, 1);
        s += __shfl_xor(s, 2);
        s += __shfl_xor(s, 4);
        if (l == 0) cbn[c] = s;
    } else if (bid < 1618) {
        int i = ((bid - 368) * 256 + tid) * 8;  // FR*KSZ = 2,560,000
        float4 a = *(const float4*)&wav[i];
        float4 b = *(const float4*)&wav[i + 4];
        split8(a, b, &wavh[i], &wavl[i]);
    } else if (bid < 1666) {
        int bid2 = bid - 1618;              // 48 blocks: 8 d x 6 s
        int d0 = (bid2 & 7) * 64;
        int sb = bid2 >> 3;
        int s0 = sb * 64;
        if (sb == 5) {                      // zero pad rows 320..383
            b8 z = {};
#pragma unroll
            for (int k = 0; k < 2; ++k) {
                int lin = tid * 2 + k;      // [0,512)
                int row = 320 + (lin >> 3);
                int col = (lin & 7) * 8;
                *(b8*)&dwfh[(size_t)row * DD + d0 + col] = z;
                *(b8*)&dwfl[(size_t)row * DD + d0 + col] = z;
            }
            return;
        }
        __shared__ float t64[64][68];
        const int u0 = 256 - s0;            // input col base (reversed range)
#pragma unroll
        for (int p = 0; p < 4; ++p) {
            int row = (tid >> 4) + 16 * p;
            int c4 = (tid & 15) * 4;
            float4 v = *(const float4*)&dw[(size_t)(d0 + row) * KSZ + u0 + c4];
            t64[row][c4] = v.x; t64[row][c4 + 1] = v.y;
            t64[row][c4 + 2] = v.z; t64[row][c4 + 3] = v.w;
        }
        __syncthreads();
        const int i = tid >> 2;             // s-local row
        const int jq = (tid & 3) * 16;      // d-local col base
        union { u16 u[8]; b8 v; } H0, L0, H1, L1;
#pragma unroll
        for (int j = 0; j < 8; ++j) {
            float m = t64[jq + j][63 - i];
            u16 h = f2bf(m);
            H0.u[j] = h; L0.u[j] = f2bf(m - bf2f(h));
            float m2 = t64[jq + 8 + j][63 - i];
            u16 h2 = f2bf(m2);
            H1.u[j] = h2; L1.u[j] = f2bf(m2 - bf2f(h2));
        }
        size_t o = (size_t)(s0 + i) * DD + d0 + jq;
        *(b8*)&dwfh[o] = H0.v; *(b8*)&dwfh[o + 8] = H1.v;
        *(b8*)&dwfl[o] = L0.v; *(b8*)&dwfl[o + 8] = L1.v;
    } else {
        // zero tavg accumulator: NB*DD = 8192 floats
        float4 z = {0.f, 0.f, 0.f, 0.f};
#pragma unroll
        for (int k = 0; k < 8; ++k)
            *(float4*)&tsum[(tid * 8 + k) * 4] = z;
    }
}

// Counted-vmcnt double-buffered pipeline (T3+T4), pure gld16 staging:
#define PIPELINE(NT, STRIDE)                                                  \
    stg(0, 0);                                                                \
    stg(1, STRIDE);                                                           \
    int cur = 0;                                                              \
    for (int t = 0; t < NT; ++t) {                                            \
        if (t < NT - 1) asm volatile("s_waitcnt vmcnt(8)" ::: "memory");      \
        else            asm volatile("s_waitcnt vmcnt(0)" ::: "memory");      \
        __builtin_amdgcn_s_barrier();                                         \
        asm volatile("" ::: "memory");                                        \
        compute(cur);                                                         \
        asm volatile("" ::: "memory");                                        \
        __builtin_amdgcn_s_barrier();                                         \
        if (t < NT - 2) stg(cur, (t + 2) * STRIDE);                           \
        cur ^= 1;                                                             \
    }

// ---------------------------------------------------------------------------
// Encoder MFMA GEMM + FUSED time-avg partials:
// emb[f,d] = wav[f,:].enc_w[d,:] + eb[d];  tsum[b,d] += sum_f emb[f,d]
// Grid 256 (1D, XCD-chunked): 64 f-panels x 4 d-panels.
// ---------------------------------------------------------------------------
__global__ __launch_bounds__(256, 2) void k_enc(const u16* __restrict__ Ahg,
                                                const u16* __restrict__ Alg,
                                                const u16* __restrict__ Bhg,
                                                const u16* __restrict__ Blg,
                                                const float* __restrict__ eb,
                                                u16* __restrict__ embh,
                                                u16* __restrict__ embl,
                                                float* __restrict__ tsum) {
    __shared__ __align__(16) u16 Ah[2][4096], Al[2][4096], Bh[2][4096], Bl[2][4096];
    __shared__ float tred[2][128][2];
    const int tid = threadIdx.x;
    const int l = tid & 63, w = tid >> 6, wm = w >> 1, wn = w & 1;
    const int lane16 = l & 15, laneK = l >> 4;
    const int g = blockIdx.x;
    const int xcd = g & 7, slot = g >> 3;
    const int f0 = (xcd * 8 + (slot & 7)) * 128;
    const int d0 = (slot >> 3) * 128;

    const int p0 = w * 128 + l, p1 = p0 + 64;
    const int r0 = p0 >> 2, q0 = (p0 & 3) ^ ((r0 >> 1) & 3);
    const int r1 = p1 >> 2, q1 = (p1 & 3) ^ ((r1 >> 1) & 3);
    int fa0 = f0 + r0; if (fa0 > FR - 1) fa0 = FR - 1;
    int fa1 = f0 + r1; if (fa1 > FR - 1) fa1 = FR - 1;
    const u16* gA0h = Ahg + (size_t)fa0 * KSZ + q0 * 8;
    const u16* gA1h = Ahg + (size_t)fa1 * KSZ + q1 * 8;
    const u16* gA0l = Alg + (size_t)fa0 * KSZ + q0 * 8;
    const u16* gA1l = Alg + (size_t)fa1 * KSZ + q1 * 8;
    const u16* gB0h = Bhg + (size_t)(d0 + r0) * KSZ + q0 * 8;
    const u16* gB1h = Bhg + (size_t)(d0 + r1) * KSZ + q1 * 8;
    const u16* gB0l = Blg + (size_t)(d0 + r0) * KSZ + q0 * 8;
    const u16* gB1l = Blg + (size_t)(d0 + r1) * KSZ + q1 * 8;

    int offA[4], offB[4];
#pragma unroll
    for (int i = 0; i < 4; ++i) {
        int ra = wm * 64 + i * 16 + lane16;
        offA[i] = (ra * 4 + (laneK ^ ((ra >> 1) & 3))) * 8;
        int rb = wn * 64 + i * 16 + lane16;
        offB[i] = (rb * 4 + (laneK ^ ((rb >> 1) & 3))) * 8;
    }

    f4 zero = {0.f, 0.f, 0.f, 0.f};
    f4 acc[4][4];
#pragma unroll
    for (int i = 0; i < 4; ++i)
#pragma unroll
        for (int j = 0; j < 4; ++j) acc[i][j] = zero;

    auto stg = [&](int buf, int kt) {
        gld16(gA0h + kt, Ah[buf] + w * 1024);
        gld16(gA1h + kt, Ah[buf] + w * 1024 + 512);
        gld16(gA0l + kt, Al[buf] + w * 1024);
        gld16(gA1l + kt, Al[buf] + w * 1024 + 512);
        gld16(gB0h + kt, Bh[buf] + w * 1024);
        gld16(gB1h + kt, Bh[buf] + w * 1024 + 512);
        gld16(gB0l + kt, Bl[buf] + w * 1024);
        gld16(gB1l + kt, Bl[buf] + w * 1024 + 512);
    };
    auto compute = [&](int buf) {
        b8 ah[4], al[4], bh[4], bl[4];
#pragma unroll
        for (int i = 0; i < 4; ++i) {
            ah[i] = *(const b8*)(Ah[buf] + offA[i]);
            al[i] = *(const b8*)(Al[buf] + offA[i]);
            bh[i] = *(const b8*)(Bh[buf] + offB[i]);
            bl[i] = *(const b8*)(Bl[buf] + offB[i]);
        }
#pragma unroll
        for (int mi = 0; mi < 4; ++mi)
#pragma unroll
            for (int ni = 0; ni < 4; ++ni) {
                acc[mi][ni] = mfma(ah[mi], bh[ni], acc[mi][ni]);
                acc[mi][ni] = mfma(ah[mi], bl[ni], acc[mi][ni]);
                acc[mi][ni] = mfma(al[mi], bh[ni], acc[mi][ni]);
            }
    };

    PIPELINE(10, 32)

    float ebv[4];
#pragma unroll
    for (int ni = 0; ni < 4; ++ni) ebv[ni] = eb[d0 + wn * 64 + ni * 16 + lane16];

    const int bA = f0 / TT;
    const int fB = min((bA + 1) * TT, f0 + 128);  // batch boundary (global f)
    float sumA[4] = {}, sumB[4] = {};
#pragma unroll
    for (int mi = 0; mi < 4; ++mi)
#pragma unroll
        for (int q = 0; q < 4; ++q) {
            int f = f0 + wm * 64 + mi * 16 + laneK * 4 + q;
            bool live = f < FR;
            bool sideA = f < fB;
#pragma unroll
            for (int ni = 0; ni < 4; ++ni) {
                int d = d0 + wn * 64 + ni * 16 + lane16;
                float v = acc[mi][ni][q] + ebv[ni];
                u16 h = f2bf(v);
                size_t o = (size_t)f * DD + d;
                embh[o] = h;
                embl[o] = f2bf(v - bf2f(h));
                if (live) { if (sideA) sumA[ni] += v; else sumB[ni] += v; }
            }
        }
    // reduce over laneK (lane bits 4..5)
#pragma unroll
    for (int m = 16; m <= 32; m <<= 1)
#pragma unroll
        for (int ni = 0; ni < 4; ++ni) {
            sumA[ni] += __shfl_xor(sumA[ni], m);
            sumB[ni] += __shfl_xor(sumB[ni], m);
        }
    if (laneK == 0)
#pragma unroll
        for (int ni = 0; ni < 4; ++ni) {
            tred[wm][wn * 64 + ni * 16 + lane16][0] = sumA[ni];
            tred[wm][wn * 64 + ni * 16 + lane16][1] = sumB[ni];
        }
    __syncthreads();
    if (tid < 128 && bA < NB) {
        float a = tred[0][tid][0] + tred[1][tid][0];
        int d = d0 + tid;
        atomicAdd(&tsum[bA * DD + d], a);
        if (fB < f0 + 128 && bA + 1 < NB) {
            float b = tred[0][tid][1] + tred[1][tid][1];
            atomicAdd(&tsum[(bA + 1) * DD + d], b);
        }
    }
}

// ---------------------------------------------------------------------------
// cond[b,i] = (tsum[b,:]/TT).lin_w[i,:] + lin_b[i]
// ---------------------------------------------------------------------------
__global__ __launch_bounds__(256) void k_cond(const float* __restrict__ tsum,
                                              const float* __restrict__ lw,
                                              const float* __restrict__ lb,
                                              float* __restrict__ cond) {
    __shared__ float stv[NB * DD];
    const float inv = 1.0f / TT;
    for (int i = threadIdx.x * 4; i < NB * DD; i += 1024) {
        float4 v = *(const float4*)&tsum[i];
        v.x *= inv; v.y *= inv; v.z *= inv; v.w *= inv;
        *(float4*)&stv[i] = v;
    }
    __syncthreads();
    const int w = threadIdx.x >> 6, lane = threadIdx.x & 63;
    const int row = blockIdx.x * 4 + w;
    float wv[8];
#pragma unroll
    for (int j = 0; j < 8; ++j) wv[j] = lw[(size_t)row * DD + lane + 64 * j];
    float r[NB];
#pragma unroll
    for (int b = 0; b < NB; ++b) {
        float s = 0.f;
#pragma unroll
        for (int j = 0; j < 8; ++j) s += wv[j] * stv[b * DD + lane + 64 * j];
        r[b] = s;
    }
#pragma unroll
    for (int m = 32; m >= 1; m >>= 1)
#pragma unroll
        for (int b = 0; b < NB; ++b) r[b] += __shfl_xor(r[b], m);
    if (lane < NB) cond[lane * DD + row] = r[lane] + lb[row];
}

__global__ __launch_bounds__(256) void k_film(const float* __restrict__ cond,
                                              const float* __restrict__ fw,
                                              const float* __restrict__ fb,
                                              float* __restrict__ gbv) {
    __shared__ float sc[NB * DD];
    for (int i = threadIdx.x * 4; i < NB * DD; i += 1024)
        *(float4*)&sc[i] = *(const float4*)&cond[i];
    __syncthreads();
    const int w = threadIdx.x >> 6, lane = threadIdx.x & 63;
    const int row = blockIdx.x * 4 + w;
    float wv[8];
#pragma unroll
    for (int j = 0; j < 8; ++j) wv[j] = fw[(size_t)row * DD + lane + 64 * j];
    float r[NB];
#pragma unroll
    for (int b = 0; b < NB; ++b) {
        float s = 0.f;
#pragma unroll
        for (int j = 0; j < 8; ++j) s += wv[j] * sc[b * DD + lane + 64 * j];
        r[b] = s;
    }
#pragma unroll
    for (int m = 32; m >= 1; m >>= 1)
#pragma unroll
        for (int b = 0; b < NB; ++b) r[b] += __shfl_xor(r[b], m);
    if (lane < NB) gbv[lane * 2 * DD + row] = r[lane] + fb[row];
}

// ---------------------------------------------------------------------------
// VQ dist MFMA v2: NO LDS staging, NO barriers in the K-loop.
// Each lane loads its MFMA fragments DIRECTLY from global (L2/L1-resident):
// fragment = 16 contiguous bytes at row*DD + laneK*8 (+kt).
// Block 128f x 128c, 4 waves (64x64 each). Grid 512 (2 blocks/CU -> 2
// waves/SIMD TLP hides L2 latency). Consecutive blocks share the B panel
// (same c-panel) -> L1 reuse. Same MFMA order as before: scores bit-identical.
// ---------------------------------------------------------------------------
__global__ __launch_bounds__(256, 2) void k_dist(const u16* __restrict__ Ahg,
                                                 const u16* __restrict__ Alg,
                                                 const u16* __restrict__ Bhg,
                                                 const u16* __restrict__ Blg,
                                                 const float* __restrict__ cbn,
                                                 float* __restrict__ pmin,
                                                 int* __restrict__ pidx) {
    __shared__ float s_best[128][2];
    __shared__ int s_bidx[128][2];
    const int tid = threadIdx.x;
    const int l = tid & 63, w = tid >> 6, wm = w >> 1, wn = w & 1;
    const int lane16 = l & 15, laneK = l >> 4;
    const int g = blockIdx.x;
    const int xcd = g & 7, loc = g >> 3;       // loc 0..63
    const int cy = loc >> 3;                   // c-panel 0..7
    const int fpl = loc & 7;                   // f-panel within XCD
    const int fbase = (xcd * 8 + fpl) * 128;   // block f origin
    const int f0 = fbase + wm * 64;
    const int c0 = cy * 128 + wn * 64;

    // per-lane fragment base pointers
    const u16 *pah[4], *pal[4], *pbh[4], *pbl[4];
#pragma unroll
    for (int i = 0; i < 4; ++i) {
        int ra = f0 + i * 16 + lane16;
        pah[i] = Ahg + (size_t)ra * DD + laneK * 8;
        pal[i] = Alg + (size_t)ra * DD + laneK * 8;
        int rb = c0 + i * 16 + lane16;
        pbh[i] = Bhg + (size_t)rb * DD + laneK * 8;
        pbl[i] = Blg + (size_t)rb * DD + laneK * 8;
    }

    f4 zero = {0.f, 0.f, 0.f, 0.f};
    f4 acc[4][4];
#pragma unroll
    for (int i = 0; i < 4; ++i)
#pragma unroll
        for (int j = 0; j < 4; ++j) acc[i][j] = zero;

    for (int kt = 0; kt < DD; kt += 32) {
        b8 bh[4], bl[4];
#pragma unroll
        for (int ni = 0; ni < 4; ++ni) {
            bh[ni] = *(const b8*)(pbh[ni] + kt);
            bl[ni] = *(const b8*)(pbl[ni] + kt);
        }
#pragma unroll
        for (int mi = 0; mi < 4; ++mi) {
            b8 ah = *(const b8*)(pah[mi] + kt);
            b8 al = *(const b8*)(pal[mi] + kt);
#pragma unroll
            for (int ni = 0; ni < 4; ++ni) {
                acc[mi][ni] = mfma(ah, bh[ni], acc[mi][ni]);
                acc[mi][ni] = mfma(ah, bl[ni], acc[mi][ni]);
                acc[mi][ni] = mfma(al, bh[ni], acc[mi][ni]);
            }
        }
    }

    float cbv[4];
    int cidx[4];
#pragma unroll
    for (int ni = 0; ni < 4; ++ni) {
        cidx[ni] = c0 + ni * 16 + lane16;
        cbv[ni] = cbn[cidx[ni]];
    }
#pragma unroll
    for (int mi = 0; mi < 4; ++mi)
#pragma unroll
        for (int q = 0; q < 4; ++q) {
            float best = 3.4e38f;
            int bi = 0x7fffffff;
#pragma unroll
            for (int ni = 0; ni < 4; ++ni) {
                float s = cbv[ni] - 2.0f * acc[mi][ni][q];
                if (s < best || (s == best && cidx[ni] < bi)) { best = s; bi = cidx[ni]; }
            }
#pragma unroll
            for (int m = 8; m >= 1; m >>= 1) {
                float os = __shfl_xor(best, m);
                int oi = __shfl_xor(bi, m);
                if (os < best || (os == best && oi < bi)) { best = os; bi = oi; }
            }
            if (lane16 == 0) {
                int rl = wm * 64 + mi * 16 + laneK * 4 + q;
                s_best[rl][wn] = best;
                s_bidx[rl][wn] = bi;
            }
        }
    __syncthreads();
    if (tid < 128) {
        float b0 = s_best[tid][0], b1 = s_best[tid][1];
        int i0 = s_bidx[tid][0], i1 = s_bidx[tid][1];
        bool t1 = (b1 < b0) || (b1 == b0 && i1 < i0);
        int f = fbase + tid;
        if (f < FR) {
            pmin[f * 8 + cy] = t1 ? b1 : b0;
            pidx[f * 8 + cy] = t1 ? i1 : i0;
        }
    }
}

// ---------------------------------------------------------------------------
// Decoder MFMA GEMM with FUSED combine + gather + FiLM + split in A-staging.
// ---------------------------------------------------------------------------
struct AV {
    float4 c00, c01, g00, g01, e00, e01;
    float4 c10, c11, g10, g11, e10, e11;
};

__global__ __launch_bounds__(256, 2) void k_dec(const float* __restrict__ pmin,
                                                const int* __restrict__ pidx,
                                                const float* __restrict__ cb,
                                                const float* __restrict__ gbv,
                                                const u16* __restrict__ Bhg,
                                                const u16* __restrict__ Blg,
                                                const float* __restrict__ db,
                                                float* __restrict__ out) {
    __shared__ __align__(16) u16 Ah[2][4096], Al[2][4096], Bh[2][4096], Bl[2][4096];
    __shared__ int codes_lds[128];
    __shared__ int b_lds[128];
    const int tid = threadIdx.x;
    const int l = tid & 63, w = tid >> 6, wm = w >> 1, wn = w & 1;
    const int lane16 = l & 15, laneK = l >> 4;
    const int f0 = blockIdx.y * 128, s0 = blockIdx.x * 128;

    // combine partial argmins -> codes for this f-panel
    if (tid < 128) {
        int f = f0 + tid;
        int fc = (f < FR) ? f : FR - 1;
        float best = pmin[fc * 8];
        int bi = pidx[fc * 8];
#pragma unroll
        for (int y = 1; y < 8; ++y) {
            float s = pmin[fc * 8 + y];
            if (s < best) { best = s; bi = pidx[fc * 8 + y]; }
        }
        codes_lds[tid] = bi;
        b_lds[tid] = fc / TT;
    }
    __syncthreads();

    // B staging (gld16)
    const int p0 = w * 128 + l, p1 = p0 + 64;
    const int r0 = p0 >> 2, q0 = (p0 & 3) ^ ((r0 >> 1) & 3);
    const int r1 = p1 >> 2, q1 = (p1 & 3) ^ ((r1 >> 1) & 3);
    const u16* gB0h = Bhg + (size_t)(s0 + r0) * DD + q0 * 8;
    const u16* gB1h = Bhg + (size_t)(s0 + r1) * DD + q1 * 8;
    const u16* gB0l = Blg + (size_t)(s0 + r0) * DD + q0 * 8;
    const u16* gB1l = Blg + (size_t)(s0 + r1) * DD + q1 * 8;

    // A staging (reg->ds_write): rows ra0 (0..63), ra1 (64..127)
    const int pa0 = tid, pa1 = tid + 256;
    const int ra0 = pa0 >> 2, qa0 = (pa0 & 3) ^ ((ra0 >> 1) & 3);
    const int ra1 = pa1 >> 2, qa1 = (pa1 & 3) ^ ((ra1 >> 1) & 3);
    const float* cp0 = cb + (size_t)codes_lds[ra0] * DD + qa0 * 8;
    const float* cp1 = cb + (size_t)codes_lds[ra1] * DD + qa1 * 8;
    const float* gp0 = gbv + b_lds[ra0] * 2 * DD + qa0 * 8;
    const float* gp1 = gbv + b_lds[ra1] * 2 * DD + qa1 * 8;

    int offA[4], offB[4];
#pragma unroll
    for (int i = 0; i < 4; ++i) {
        int ra = wm * 64 + i * 16 + lane16;
        offA[i] = (ra * 4 + (laneK ^ ((ra >> 1) & 3))) * 8;
        int rb = wn * 64 + i * 16 + lane16;
        offB[i] = (rb * 4 + (laneK ^ ((rb >> 1) & 3))) * 8;
    }

    f4 zero = {0.f, 0.f, 0.f, 0.f};
    f4 acc[4][4];
#pragma unroll
    for (int i = 0; i < 4; ++i)
#pragma unroll
        for (int j = 0; j < 4; ++j) acc[i][j] = zero;

    auto stgB = [&](int buf, int kt) {
        gld16(gB0h + kt, Bh[buf] + w * 1024);
        gld16(gB1h + kt, Bh[buf] + w * 1024 + 512);
        gld16(gB0l + kt, Bl[buf] + w * 1024);
        gld16(gB1l + kt, Bl[buf] + w * 1024 + 512);
    };
    auto loadA = [&](int kt) {
        AV v;
        v.c00 = *(const float4*)(cp0 + kt);
        v.c01 = *(const float4*)(cp0 + kt + 4);
        v.g00 = *(const float4*)(gp0 + kt);
        v.g01 = *(const float4*)(gp0 + kt + 4);
        v.e00 = *(const float4*)(gp0 + DD + kt);
        v.e01 = *(const float4*)(gp0 + DD + kt + 4);
        v.c10 = *(const float4*)(cp1 + kt);
        v.c11 = *(const float4*)(cp1 + kt + 4);
        v.g10 = *(const float4*)(gp1 + kt);
        v.g11 = *(const float4*)(gp1 + kt + 4);
        v.e10 = *(const float4*)(gp1 + DD + kt);
        v.e11 = *(const float4*)(gp1 + DD + kt + 4);
        return v;
    };
    auto writeA = [&](int buf, const AV& v) {
        float4 m00, m01, m10, m11;
        m00.x = v.g00.x * v.c00.x + v.e00.x; m00.y = v.g00.y * v.c00.y + v.e00.y;
        m00.z = v.g00.z * v.c00.z + v.e00.z; m00.w = v.g00.w * v.c00.w + v.e00.w;
        m01.x = v.g01.x * v.c01.x + v.e01.x; m01.y = v.g01.y * v.c01.y + v.e01.y;
        m01.z = v.g01.z * v.c01.z + v.e01.z; m01.w = v.g01.w * v.c01.w + v.e01.w;
        m10.x = v.g10.x * v.c10.x + v.e10.x; m10.y = v.g10.y * v.c10.y + v.e10.y;
        m10.z = v.g10.z * v.c10.z + v.e10.z; m10.w = v.g10.w * v.c10.w + v.e10.w;
        m11.x = v.g11.x * v.c11.x + v.e11.x; m11.y = v.g11.y * v.c11.y + v.e11.y;
        m11.z = v.g11.z * v.c11.z + v.e11.z; m11.w = v.g11.w * v.c11.w + v.e11.w;
        split8(m00, m01, Ah[buf] + pa0 * 8, Al[buf] + pa0 * 8);
        split8(m10, m11, Ah[buf] + pa1 * 8, Al[buf] + pa1 * 8);
    };
    auto compute = [&](int buf) {
        b8 ah[4], al[4], bh[4], bl[4];
#pragma unroll
        for (int i = 0; i < 4; ++i) {
            ah[i] = *(const b8*)(Ah[buf] + offA[i]);
            al[i] = *(const b8*)(Al[buf] + offA[i]);
            bh[i] = *(const b8*)(Bh[buf] + offB[i]);
            bl[i] = *(const b8*)(Bl[buf] + offB[i]);
        }
#pragma unroll
        for (int mi = 0; mi < 4; ++mi)
#pragma unroll
            for (int ni = 0; ni < 4; ++ni) {
                acc[mi][ni] = mfma(ah[mi], bh[ni], acc[mi][ni]);
                acc[mi][ni] = mfma(ah[mi], bl[ni], acc[mi][ni]);
                acc[mi][ni] = mfma(al[mi], bh[ni], acc[mi][ni]);
            }
    };

    // prologue: A floats first (older), then gld16s, then writes
    {
        AV v0 = loadA(0);
        AV v1 = loadA(32);
        stgB(0, 0);
        stgB(1, 32);
        writeA(0, v0);
        writeA(1, v1);
    }
    int cur = 0;
    for (int t = 0; t < 16; ++t) {
        if (t < 15) asm volatile("s_waitcnt vmcnt(4) lgkmcnt(0)" ::: "memory");
        else        asm volatile("s_waitcnt vmcnt(0) lgkmcnt(0)" ::: "memory");
        __builtin_amdgcn_s_barrier();
        asm volatile("" ::: "memory");
        compute(cur);
        asm volatile("" ::: "memory");
        __builtin_amdgcn_s_barrier();
        if (t < 14) {
            AV v = loadA((t + 2) * 32);   // floats issued before gld16s
            stgB(cur, (t + 2) * 32);
            writeA(cur, v);
        }
        cur ^= 1;
    }

    const float d0v = db[0];
#pragma unroll
    for (int mi = 0; mi < 4; ++mi)
#pragma unroll
        for (int q = 0; q < 4; ++q) {
            int f = f0 + wm * 64 + mi * 16 + laneK * 4 + q;
            if (f < FR) {
#pragma unroll
                for (int ni = 0; ni < 4; ++ni) {
                    int s = s0 + wn * 64 + ni * 16 + lane16;
                    if (s < KSZ) out[(size_t)f * KSZ + s] = acc[mi][ni][q] + d0v;
                }
            }
        }
}

// ---------------------------------------------------------------------------
extern "C" void kernel_launch(void* const* d_in, const int* in_sizes, int n_in,
                              void* d_out, int out_size, void* d_ws, size_t ws_size,
                              hipStream_t stream) {
    const float* wav    = (const float*)d_in[0];
    const float* enc_w  = (const float*)d_in[1];
    const float* enc_b  = (const float*)d_in[2];
    const float* cb     = (const float*)d_in[3];
    const float* lin_w  = (const float*)d_in[4];
    const float* lin_b  = (const float*)d_in[5];
    const float* film_w = (const float*)d_in[6];
    const float* film_b = (const float*)d_in[7];
    const float* dec_w  = (const float*)d_in[8];
    const float* dec_b  = (const float*)d_in[9];
    float* out = (float*)d_out;

    char* p = (char*)d_ws;
    u16* embh = (u16*)p;                 p += (size_t)FRP * DD * 2;
    u16* embl = (u16*)p;                 p += (size_t)FRP * DD * 2;
    u16* wavh = (u16*)p;                 p += (size_t)FR * KSZ * 2;
    u16* wavl = (u16*)p;                 p += (size_t)FR * KSZ * 2;
    u16* ewh  = (u16*)p;                 p += (size_t)DD * KSZ * 2;
    u16* ewl  = (u16*)p;                 p += (size_t)DD * KSZ * 2;
    u16* cbh  = (u16*)p;                 p += (size_t)CK * DD * 2;
    u16* cbl  = (u16*)p;                 p += (size_t)CK * DD * 2;
    u16* dwfh = (u16*)p;                 p += (size_t)384 * DD * 2;
    u16* dwfl = (u16*)p;                 p += (size_t)384 * DD * 2;
    float* cbn  = (float*)p;             p += CK * 4;
    float* tsum = (float*)p;             p += NB * DD * 4;
    float* cond = (float*)p;             p += NB * DD * 4;
    float* gbv  = (float*)p;             p += NB * 2 * DD * 4;
    float* pmin = (float*)p;             p += FR * 8 * 4;
    int*   pidx = (int*)p;               p += FR * 8 * 4;

    k_prep<<<dim3(1667), 256, 0, stream>>>(enc_w, ewh, ewl, cb, cbh, cbl,
                                           dec_w, dwfh, dwfl, cbn, wav, wavh, wavl, tsum);
    k_enc<<<dim3(256), 256, 0, stream>>>(wavh, wavl, ewh, ewl, enc_b, embh, embl, tsum);
    k_cond<<<dim3(128), 256, 0, stream>>>(tsum, lin_w, lin_b, cond);
    k_film<<<dim3(256), 256, 0, stream>>>(cond, film_w, film_b, gbv);
    k_dist<<<dim3(512), 256, 0, stream>>>(embh, embl, cbh, cbl, cbn, pmin, pidx);
    k_dec<<<dim3(3, 63), 256, 0, stream>>>(pmin, pidx, cb, gbv, dwfh, dwfl, dec_b, out);
}

// Round 9
// 172.197 us; speedup vs baseline: 1.2164x; 1.2164x over previous
//
#include <hip/hip_runtime.h>

#define FR   8000
#define FRP  8192    // padded to 64*128 for XCD-chunked dist mapping
#define DD   512
#define CK   1024
#define KSZ  320
#define TT   500
#define NB   16

typedef unsigned int u32;
typedef unsigned short u16;
typedef __attribute__((ext_vector_type(8))) short b8;   // 8 x bf16 bits
typedef __attribute__((ext_vector_type(4))) float f4;

__device__ __forceinline__ float bf2f(u16 h) {
    u32 u = ((u32)h) << 16;
    return __builtin_bit_cast(float, u);
}
__device__ __forceinline__ u16 f2bf(float f) {  // RNE
    u32 u = __builtin_bit_cast(u32, f);
    u32 r = u + 0x7FFFu + ((u >> 16) & 1u);
    return (u16)(r >> 16);
}

__device__ __forceinline__ void gld16(const u16* g, u16* s) {
    __builtin_amdgcn_global_load_lds(
        (const __attribute__((address_space(1))) u32*)g,
        (__attribute__((address_space(3))) u32*)s, 16, 0, 0);
}

__device__ __forceinline__ f4 mfma(b8 a, b8 b, f4 c) {
    return __builtin_amdgcn_mfma_f32_16x16x32_bf16(a, b, c, 0, 0, 0);
}

__device__ __forceinline__ void split8(float4 a, float4 b, u16* dh, u16* dl) {
    float xs[8] = {a.x, a.y, a.z, a.w, b.x, b.y, b.z, b.w};
    union { u16 u[8]; b8 v; } H, L;
#pragma unroll
    for (int i = 0; i < 8; ++i) {
        u16 h = f2bf(xs[i]);
        H.u[i] = h;
        L.u[i] = f2bf(xs[i] - bf2f(h));
    }
    *(b8*)dh = H.v;
    *(b8*)dl = L.v;
}

// ---------------------------------------------------------------------------
// Merged prep (wav split now fused into k_enc):
//  [0,80)    split enc_w
//  [80,336)  split cb
//  [336,368) cbnorm
//  [368,416) dwf transpose: dwf[s][d] = dec_w[d][319-s], rows 320..383 zero
//  [416]     zero tavg accumulator (for k_enc atomics)
// ---------------------------------------------------------------------------
__global__ __launch_bounds__(256) void k_prep(const float* __restrict__ enc_w,
                                              u16* __restrict__ ewh, u16* __restrict__ ewl,
                                              const float* __restrict__ cb,
                                              u16* __restrict__ cbh, u16* __restrict__ cbl,
                                              const float* __restrict__ dw,
                                              u16* __restrict__ dwfh, u16* __restrict__ dwfl,
                                              float* __restrict__ cbn,
                                              float* __restrict__ tsum) {
    const int bid = blockIdx.x, tid = threadIdx.x;
    if (bid < 80) {
        int i = (bid * 256 + tid) * 8;
        float4 a = *(const float4*)&enc_w[i];
        float4 b = *(const float4*)&enc_w[i + 4];
        split8(a, b, &ewh[i], &ewl[i]);
    } else if (bid < 336) {
        int i = ((bid - 80) * 256 + tid) * 8;
        float4 a = *(const float4*)&cb[i];
        float4 b = *(const float4*)&cb[i + 4];
        split8(a, b, &cbh[i], &cbl[i]);
    } else if (bid < 368) {
        int c = (bid - 336) * 32 + (tid >> 3);
        int l = tid & 7;
        float s = 0.f;
        for (int j = l * 4; j < DD; j += 32) {
            float4 v = *(const float4*)&cb[c * DD + j];
            s += v.x * v.x + v.y * v.y + v.z * v.z + v.w * v.w;
        }
        s += __shfl_xor(s, 1);
        s += __shfl_xor(s, 2);
        s += __shfl_xor(s, 4);
        if (l == 0) cbn[c] = s;
    } else if (bid < 416) {
        int bid2 = bid - 368;               // 48 blocks: 8 d x 6 s
        int d0 = (bid2 & 7) * 64;
        int sb = bid2 >> 3;
        int s0 = sb * 64;
        if (sb == 5) {                      // zero pad rows 320..383
            b8 z = {};
#pragma unroll
            for (int k = 0; k < 2; ++k) {
                int lin = tid * 2 + k;      // [0,512)
                int row = 320 + (lin >> 3);
                int col = (lin & 7) * 8;
                *(b8*)&dwfh[(size_t)row * DD + d0 + col] = z;
                *(b8*)&dwfl[(size_t)row * DD + d0 + col] = z;
            }
            return;
        }
        __shared__ float t64[64][68];
        const int u0 = 256 - s0;            // input col base (reversed range)
#pragma unroll
        for (int p = 0; p < 4; ++p) {
            int row = (tid >> 4) + 16 * p;
            int c4 = (tid & 15) * 4;
            float4 v = *(const float4*)&dw[(size_t)(d0 + row) * KSZ + u0 + c4];
            t64[row][c4] = v.x; t64[row][c4 + 1] = v.y;
            t64[row][c4 + 2] = v.z; t64[row][c4 + 3] = v.w;
        }
        __syncthreads();
        const int i = tid >> 2;             // s-local row
        const int jq = (tid & 3) * 16;      // d-local col base
        union { u16 u[8]; b8 v; } H0, L0, H1, L1;
#pragma unroll
        for (int j = 0; j < 8; ++j) {
            float m = t64[jq + j][63 - i];
            u16 h = f2bf(m);
            H0.u[j] = h; L0.u[j] = f2bf(m - bf2f(h));
            float m2 = t64[jq + 8 + j][63 - i];
            u16 h2 = f2bf(m2);
            H1.u[j] = h2; L1.u[j] = f2bf(m2 - bf2f(h2));
        }
        size_t o = (size_t)(s0 + i) * DD + d0 + jq;
        *(b8*)&dwfh[o] = H0.v; *(b8*)&dwfh[o + 8] = H1.v;
        *(b8*)&dwfl[o] = L0.v; *(b8*)&dwfl[o + 8] = L1.v;
    } else {
        // zero tavg accumulator: NB*DD = 8192 floats
        float4 z = {0.f, 0.f, 0.f, 0.f};
#pragma unroll
        for (int k = 0; k < 8; ++k)
            *(float4*)&tsum[(tid * 8 + k) * 4] = z;
    }
}

// Counted-vmcnt double-buffered pipeline (T3+T4), pure gld16 staging:
#define PIPELINE(NT, STRIDE)                                                  \
    stg(0, 0);                                                                \
    stg(1, STRIDE);                                                           \
    int cur = 0;                                                              \
    for (int t = 0; t < NT; ++t) {                                            \
        if (t < NT - 1) asm volatile("s_waitcnt vmcnt(8)" ::: "memory");      \
        else            asm volatile("s_waitcnt vmcnt(0)" ::: "memory");      \
        __builtin_amdgcn_s_barrier();                                         \
        asm volatile("" ::: "memory");                                        \
        compute(cur);                                                         \
        asm volatile("" ::: "memory");                                        \
        __builtin_amdgcn_s_barrier();                                         \
        if (t < NT - 2) stg(cur, (t + 2) * STRIDE);                           \
        cur ^= 1;                                                             \
    }

// ---------------------------------------------------------------------------
// Encoder MFMA GEMM + FUSED wav split (A reg-staged) + FUSED time-avg:
// emb[f,d] = wav[f,:].enc_w[d,:] + eb[d];  tsum[b,d] += sum_f emb[f,d]
// Grid 256 (1D, XCD-chunked): 64 f-panels x 4 d-panels.
// Issue order per step: A float4 loads -> B gld16 -> split8/ds_write, so
// the vmcnt(4) wait leaves next tile's B prefetch in flight.
// ---------------------------------------------------------------------------
struct AW { float4 x0, x1, y0, y1; };

__global__ __launch_bounds__(256, 2) void k_enc(const float* __restrict__ wav,
                                                const u16* __restrict__ Bhg,
                                                const u16* __restrict__ Blg,
                                                const float* __restrict__ eb,
                                                u16* __restrict__ embh,
                                                u16* __restrict__ embl,
                                                float* __restrict__ tsum) {
    __shared__ __align__(16) u16 Ah[2][4096], Al[2][4096], Bh[2][4096], Bl[2][4096];
    __shared__ float tred[2][128][2];
    const int tid = threadIdx.x;
    const int l = tid & 63, w = tid >> 6, wm = w >> 1, wn = w & 1;
    const int lane16 = l & 15, laneK = l >> 4;
    const int g = blockIdx.x;
    const int xcd = g & 7, slot = g >> 3;
    const int f0 = (xcd * 8 + (slot & 7)) * 128;
    const int d0 = (slot >> 3) * 128;

    // B staging decode (gld16)
    const int p0 = w * 128 + l, p1 = p0 + 64;
    const int r0 = p0 >> 2, q0 = (p0 & 3) ^ ((r0 >> 1) & 3);
    const int r1 = p1 >> 2, q1 = (p1 & 3) ^ ((r1 >> 1) & 3);
    const u16* gB0h = Bhg + (size_t)(d0 + r0) * KSZ + q0 * 8;
    const u16* gB1h = Bhg + (size_t)(d0 + r1) * KSZ + q1 * 8;
    const u16* gB0l = Blg + (size_t)(d0 + r0) * KSZ + q0 * 8;
    const u16* gB1l = Blg + (size_t)(d0 + r1) * KSZ + q1 * 8;

    // A staging decode (reg convert from fp32 wav)
    const int pa0 = tid, pa1 = tid + 256;
    const int ra0 = pa0 >> 2, qa0 = (pa0 & 3) ^ ((ra0 >> 1) & 3);
    const int ra1 = pa1 >> 2, qa1 = (pa1 & 3) ^ ((ra1 >> 1) & 3);
    int fa0 = f0 + ra0; if (fa0 > FR - 1) fa0 = FR - 1;
    int fa1 = f0 + ra1; if (fa1 > FR - 1) fa1 = FR - 1;
    const float* wv0 = wav + (size_t)fa0 * KSZ + qa0 * 8;
    const float* wv1 = wav + (size_t)fa1 * KSZ + qa1 * 8;

    int offA[4], offB[4];
#pragma unroll
    for (int i = 0; i < 4; ++i) {
        int ra = wm * 64 + i * 16 + lane16;
        offA[i] = (ra * 4 + (laneK ^ ((ra >> 1) & 3))) * 8;
        int rb = wn * 64 + i * 16 + lane16;
        offB[i] = (rb * 4 + (laneK ^ ((rb >> 1) & 3))) * 8;
    }

    f4 zero = {0.f, 0.f, 0.f, 0.f};
    f4 acc[4][4];
#pragma unroll
    for (int i = 0; i < 4; ++i)
#pragma unroll
        for (int j = 0; j < 4; ++j) acc[i][j] = zero;

    auto loadA = [&](int kt) {
        AW v;
        v.x0 = *(const float4*)(wv0 + kt);
        v.x1 = *(const float4*)(wv0 + kt + 4);
        v.y0 = *(const float4*)(wv1 + kt);
        v.y1 = *(const float4*)(wv1 + kt + 4);
        return v;
    };
    auto writeA = [&](int buf, const AW& v) {
        split8(v.x0, v.x1, Ah[buf] + pa0 * 8, Al[buf] + pa0 * 8);
        split8(v.y0, v.y1, Ah[buf] + pa1 * 8, Al[buf] + pa1 * 8);
    };
    auto stgB = [&](int buf, int kt) {
        gld16(gB0h + kt, Bh[buf] + w * 1024);
        gld16(gB1h + kt, Bh[buf] + w * 1024 + 512);
        gld16(gB0l + kt, Bl[buf] + w * 1024);
        gld16(gB1l + kt, Bl[buf] + w * 1024 + 512);
    };
    auto compute = [&](int buf) {
        b8 ah[4], al[4], bh[4], bl[4];
#pragma unroll
        for (int i = 0; i < 4; ++i) {
            ah[i] = *(const b8*)(Ah[buf] + offA[i]);
            al[i] = *(const b8*)(Al[buf] + offA[i]);
            bh[i] = *(const b8*)(Bh[buf] + offB[i]);
            bl[i] = *(const b8*)(Bl[buf] + offB[i]);
        }
#pragma unroll
        for (int mi = 0; mi < 4; ++mi)
#pragma unroll
            for (int ni = 0; ni < 4; ++ni) {
                acc[mi][ni] = mfma(ah[mi], bh[ni], acc[mi][ni]);
                acc[mi][ni] = mfma(ah[mi], bl[ni], acc[mi][ni]);
                acc[mi][ni] = mfma(al[mi], bh[ni], acc[mi][ni]);
            }
    };

    // prologue: A floats first (older), then gld16s, then writes
    {
        AW v0 = loadA(0);
        AW v1 = loadA(32);
        stgB(0, 0);
        stgB(1, 32);
        writeA(0, v0);
        writeA(1, v1);
    }
    int cur = 0;
    for (int t = 0; t < 10; ++t) {
        if (t < 9) asm volatile("s_waitcnt vmcnt(4) lgkmcnt(0)" ::: "memory");
        else       asm volatile("s_waitcnt vmcnt(0) lgkmcnt(0)" ::: "memory");
        __builtin_amdgcn_s_barrier();
        asm volatile("" ::: "memory");
        compute(cur);
        asm volatile("" ::: "memory");
        __builtin_amdgcn_s_barrier();
        if (t < 8) {
            AW v = loadA((t + 2) * 32);   // floats issued before gld16s
            stgB(cur, (t + 2) * 32);
            writeA(cur, v);
        }
        cur ^= 1;
    }

    float ebv[4];
#pragma unroll
    for (int ni = 0; ni < 4; ++ni) ebv[ni] = eb[d0 + wn * 64 + ni * 16 + lane16];

    const int bA = f0 / TT;
    const int fB = min((bA + 1) * TT, f0 + 128);  // batch boundary (global f)
    float sumA[4] = {}, sumB[4] = {};
#pragma unroll
    for (int mi = 0; mi < 4; ++mi)
#pragma unroll
        for (int q = 0; q < 4; ++q) {
            int f = f0 + wm * 64 + mi * 16 + laneK * 4 + q;
            bool live = f < FR;
            bool sideA = f < fB;
#pragma unroll
            for (int ni = 0; ni < 4; ++ni) {
                int d = d0 + wn * 64 + ni * 16 + lane16;
                float v = acc[mi][ni][q] + ebv[ni];
                u16 h = f2bf(v);
                size_t o = (size_t)f * DD + d;
                embh[o] = h;
                embl[o] = f2bf(v - bf2f(h));
                if (live) { if (sideA) sumA[ni] += v; else sumB[ni] += v; }
            }
        }
    // reduce over laneK (lane bits 4..5)
#pragma unroll
    for (int m = 16; m <= 32; m <<= 1)
#pragma unroll
        for (int ni = 0; ni < 4; ++ni) {
            sumA[ni] += __shfl_xor(sumA[ni], m);
            sumB[ni] += __shfl_xor(sumB[ni], m);
        }
    if (laneK == 0)
#pragma unroll
        for (int ni = 0; ni < 4; ++ni) {
            tred[wm][wn * 64 + ni * 16 + lane16][0] = sumA[ni];
            tred[wm][wn * 64 + ni * 16 + lane16][1] = sumB[ni];
        }
    __syncthreads();
    if (tid < 128 && bA < NB) {
        float a = tred[0][tid][0] + tred[1][tid][0];
        int d = d0 + tid;
        atomicAdd(&tsum[bA * DD + d], a);
        if (fB < f0 + 128 && bA + 1 < NB) {
            float b = tred[0][tid][1] + tred[1][tid][1];
            atomicAdd(&tsum[(bA + 1) * DD + d], b);
        }
    }
}

// ---------------------------------------------------------------------------
// cond[b,i] = (tsum[b,:]/TT).lin_w[i,:] + lin_b[i]
// ---------------------------------------------------------------------------
__global__ __launch_bounds__(256) void k_cond(const float* __restrict__ tsum,
                                              const float* __restrict__ lw,
                                              const float* __restrict__ lb,
                                              float* __restrict__ cond) {
    __shared__ float stv[NB * DD];
    const float inv = 1.0f / TT;
    for (int i = threadIdx.x * 4; i < NB * DD; i += 1024) {
        float4 v = *(const float4*)&tsum[i];
        v.x *= inv; v.y *= inv; v.z *= inv; v.w *= inv;
        *(float4*)&stv[i] = v;
    }
    __syncthreads();
    const int w = threadIdx.x >> 6, lane = threadIdx.x & 63;
    const int row = blockIdx.x * 4 + w;
    float wv[8];
#pragma unroll
    for (int j = 0; j < 8; ++j) wv[j] = lw[(size_t)row * DD + lane + 64 * j];
    float r[NB];
#pragma unroll
    for (int b = 0; b < NB; ++b) {
        float s = 0.f;
#pragma unroll
        for (int j = 0; j < 8; ++j) s += wv[j] * stv[b * DD + lane + 64 * j];
        r[b] = s;
    }
#pragma unroll
    for (int m = 32; m >= 1; m >>= 1)
#pragma unroll
        for (int b = 0; b < NB; ++b) r[b] += __shfl_xor(r[b], m);
    if (lane < NB) cond[lane * DD + row] = r[lane] + lb[row];
}

__global__ __launch_bounds__(256) void k_film(const float* __restrict__ cond,
                                              const float* __restrict__ fw,
                                              const float* __restrict__ fb,
                                              float* __restrict__ gbv) {
    __shared__ float sc[NB * DD];
    for (int i = threadIdx.x * 4; i < NB * DD; i += 1024)
        *(float4*)&sc[i] = *(const float4*)&cond[i];
    __syncthreads();
    const int w = threadIdx.x >> 6, lane = threadIdx.x & 63;
    const int row = blockIdx.x * 4 + w;
    float wv[8];
#pragma unroll
    for (int j = 0; j < 8; ++j) wv[j] = fw[(size_t)row * DD + lane + 64 * j];
    float r[NB];
#pragma unroll
    for (int b = 0; b < NB; ++b) {
        float s = 0.f;
#pragma unroll
        for (int j = 0; j < 8; ++j) s += wv[j] * sc[b * DD + lane + 64 * j];
        r[b] = s;
    }
#pragma unroll
    for (int m = 32; m >= 1; m >>= 1)
#pragma unroll
        for (int b = 0; b < NB; ++b) r[b] += __shfl_xor(r[b], m);
    if (lane < NB) gbv[lane * 2 * DD + row] = r[lane] + fb[row];
}

// ---------------------------------------------------------------------------
// VQ dist MFMA + fused per-block argmin (R7 LDS pipeline — reverted from the
// failed direct-global experiment). Grid 512 (1D, XCD-chunked).
// ---------------------------------------------------------------------------
__global__ __launch_bounds__(256, 2) void k_dist(const u16* __restrict__ Ahg,
                                                 const u16* __restrict__ Alg,
                                                 const u16* __restrict__ Bhg,
                                                 const u16* __restrict__ Blg,
                                                 const float* __restrict__ cbn,
                                                 float* __restrict__ pmin,
                                                 int* __restrict__ pidx) {
    __shared__ __align__(16) u16 Ah[2][4096], Al[2][4096], Bh[2][4096], Bl[2][4096];
    __shared__ float s_best[128][2];
    __shared__ int s_bidx[128][2];
    const int tid = threadIdx.x;
    const int l = tid & 63, w = tid >> 6, wm = w >> 1, wn = w & 1;
    const int lane16 = l & 15, laneK = l >> 4;
    const int g = blockIdx.x;
    const int xcd = g & 7, slot = g >> 3;
    const int f0 = (xcd * 8 + (slot & 7)) * 128;
    const int cy = slot >> 3;
    const int c0 = cy * 128;

    const int p0 = w * 128 + l, p1 = p0 + 64;
    const int r0 = p0 >> 2, q0 = (p0 & 3) ^ ((r0 >> 1) & 3);
    const int r1 = p1 >> 2, q1 = (p1 & 3) ^ ((r1 >> 1) & 3);
    const u16* gA0h = Ahg + (size_t)(f0 + r0) * DD + q0 * 8;
    const u16* gA1h = Ahg + (size_t)(f0 + r1) * DD + q1 * 8;
    const u16* gA0l = Alg + (size_t)(f0 + r0) * DD + q0 * 8;
    const u16* gA1l = Alg + (size_t)(f0 + r1) * DD + q1 * 8;
    const u16* gB0h = Bhg + (size_t)(c0 + r0) * DD + q0 * 8;
    const u16* gB1h = Bhg + (size_t)(c0 + r1) * DD + q1 * 8;
    const u16* gB0l = Blg + (size_t)(c0 + r0) * DD + q0 * 8;
    const u16* gB1l = Blg + (size_t)(c0 + r1) * DD + q1 * 8;

    int offA[4], offB[4];
#pragma unroll
    for (int i = 0; i < 4; ++i) {
        int ra = wm * 64 + i * 16 + lane16;
        offA[i] = (ra * 4 + (laneK ^ ((ra >> 1) & 3))) * 8;
        int rb = wn * 64 + i * 16 + lane16;
        offB[i] = (rb * 4 + (laneK ^ ((rb >> 1) & 3))) * 8;
    }

    f4 zero = {0.f, 0.f, 0.f, 0.f};
    f4 acc[4][4];
#pragma unroll
    for (int i = 0; i < 4; ++i)
#pragma unroll
        for (int j = 0; j < 4; ++j) acc[i][j] = zero;

    auto stg = [&](int buf, int kt) {
        gld16(gA0h + kt, Ah[buf] + w * 1024);
        gld16(gA1h + kt, Ah[buf] + w * 1024 + 512);
        gld16(gA0l + kt, Al[buf] + w * 1024);
        gld16(gA1l + kt, Al[buf] + w * 1024 + 512);
        gld16(gB0h + kt, Bh[buf] + w * 1024);
        gld16(gB1h + kt, Bh[buf] + w * 1024 + 512);
        gld16(gB0l + kt, Bl[buf] + w * 1024);
        gld16(gB1l + kt, Bl[buf] + w * 1024 + 512);
    };
    auto compute = [&](int buf) {
        b8 ah[4], al[4], bh[4], bl[4];
#pragma unroll
        for (int i = 0; i < 4; ++i) {
            ah[i] = *(const b8*)(Ah[buf] + offA[i]);
            al[i] = *(const b8*)(Al[buf] + offA[i]);
            bh[i] = *(const b8*)(Bh[buf] + offB[i]);
            bl[i] = *(const b8*)(Bl[buf] + offB[i]);
        }
#pragma unroll
        for (int mi = 0; mi < 4; ++mi)
#pragma unroll
            for (int ni = 0; ni < 4; ++ni) {
                acc[mi][ni] = mfma(ah[mi], bh[ni], acc[mi][ni]);
                acc[mi][ni] = mfma(ah[mi], bl[ni], acc[mi][ni]);
                acc[mi][ni] = mfma(al[mi], bh[ni], acc[mi][ni]);
            }
    };

    PIPELINE(16, 32)

    float cbv[4];
    int cidx[4];
#pragma unroll
    for (int ni = 0; ni < 4; ++ni) {
        cidx[ni] = c0 + wn * 64 + ni * 16 + lane16;
        cbv[ni] = cbn[cidx[ni]];
    }
#pragma unroll
    for (int mi = 0; mi < 4; ++mi)
#pragma unroll
        for (int q = 0; q < 4; ++q) {
            float best = 3.4e38f;
            int bi = 0x7fffffff;
#pragma unroll
            for (int ni = 0; ni < 4; ++ni) {
                float s = cbv[ni] - 2.0f * acc[mi][ni][q];
                if (s < best || (s == best && cidx[ni] < bi)) { best = s; bi = cidx[ni]; }
            }
#pragma unroll
            for (int m = 8; m >= 1; m >>= 1) {
                float os = __shfl_xor(best, m);
                int oi = __shfl_xor(bi, m);
                if (os < best || (os == best && oi < bi)) { best = os; bi = oi; }
            }
            if (lane16 == 0) {
                int rl = wm * 64 + mi * 16 + laneK * 4 + q;
                s_best[rl][wn] = best;
                s_bidx[rl][wn] = bi;
            }
        }
    __syncthreads();
    if (tid < 128) {
        float b0 = s_best[tid][0], b1 = s_best[tid][1];
        int i0 = s_bidx[tid][0], i1 = s_bidx[tid][1];
        bool t1 = (b1 < b0) || (b1 == b0 && i1 < i0);
        int f = f0 + tid;
        if (f < FR) {
            pmin[f * 8 + cy] = t1 ? b1 : b0;
            pidx[f * 8 + cy] = t1 ? i1 : i0;
        }
    }
}

// ---------------------------------------------------------------------------
// Decoder MFMA GEMM with FUSED combine + gather + FiLM + split in A-staging.
// ---------------------------------------------------------------------------
struct AV {
    float4 c00, c01, g00, g01, e00, e01;
    float4 c10, c11, g10, g11, e10, e11;
};

__global__ __launch_bounds__(256, 2) void k_dec(const float* __restrict__ pmin,
                                                const int* __restrict__ pidx,
                                                const float* __restrict__ cb,
                                                const float* __restrict__ gbv,
                                                const u16* __restrict__ Bhg,
                                                const u16* __restrict__ Blg,
                                                const float* __restrict__ db,
                                                float* __restrict__ out) {
    __shared__ __align__(16) u16 Ah[2][4096], Al[2][4096], Bh[2][4096], Bl[2][4096];
    __shared__ int codes_lds[128];
    __shared__ int b_lds[128];
    const int tid = threadIdx.x;
    const int l = tid & 63, w = tid >> 6, wm = w >> 1, wn = w & 1;
    const int lane16 = l & 15, laneK = l >> 4;
    const int f0 = blockIdx.y * 128, s0 = blockIdx.x * 128;

    // combine partial argmins -> codes for this f-panel
    if (tid < 128) {
        int f = f0 + tid;
        int fc = (f < FR) ? f : FR - 1;
        float best = pmin[fc * 8];
        int bi = pidx[fc * 8];
#pragma unroll
        for (int y = 1; y < 8; ++y) {
            float s = pmin[fc * 8 + y];
            if (s < best) { best = s; bi = pidx[fc * 8 + y]; }
        }
        codes_lds[tid] = bi;
        b_lds[tid] = fc / TT;
    }
    __syncthreads();

    // B staging (gld16)
    const int p0 = w * 128 + l, p1 = p0 + 64;
    const int r0 = p0 >> 2, q0 = (p0 & 3) ^ ((r0 >> 1) & 3);
    const int r1 = p1 >> 2, q1 = (p1 & 3) ^ ((r1 >> 1) & 3);
    const u16* gB0h = Bhg + (size_t)(s0 + r0) * DD + q0 * 8;
    const u16* gB1h = Bhg + (size_t)(s0 + r1) * DD + q1 * 8;
    const u16* gB0l = Blg + (size_t)(s0 + r0) * DD + q0 * 8;
    const u16* gB1l = Blg + (size_t)(s0 + r1) * DD + q1 * 8;

    // A staging (reg->ds_write): rows ra0 (0..63), ra1 (64..127)
    const int pa0 = tid, pa1 = tid + 256;
    const int ra0 = pa0 >> 2, qa0 = (pa0 & 3) ^ ((ra0 >> 1) & 3);
    const int ra1 = pa1 >> 2, qa1 = (pa1 & 3) ^ ((ra1 >> 1) & 3);
    const float* cp0 = cb + (size_t)codes_lds[ra0] * DD + qa0 * 8;
    const float* cp1 = cb + (size_t)codes_lds[ra1] * DD + qa1 * 8;
    const float* gp0 = gbv + b_lds[ra0] * 2 * DD + qa0 * 8;
    const float* gp1 = gbv + b_lds[ra1] * 2 * DD + qa1 * 8;

    int offA[4], offB[4];
#pragma unroll
    for (int i = 0; i < 4; ++i) {
        int ra = wm * 64 + i * 16 + lane16;
        offA[i] = (ra * 4 + (laneK ^ ((ra >> 1) & 3))) * 8;
        int rb = wn * 64 + i * 16 + lane16;
        offB[i] = (rb * 4 + (laneK ^ ((rb >> 1) & 3))) * 8;
    }

    f4 zero = {0.f, 0.f, 0.f, 0.f};
    f4 acc[4][4];
#pragma unroll
    for (int i = 0; i < 4; ++i)
#pragma unroll
        for (int j = 0; j < 4; ++j) acc[i][j] = zero;

    auto stgB = [&](int buf, int kt) {
        gld16(gB0h + kt, Bh[buf] + w * 1024);
        gld16(gB1h + kt, Bh[buf] + w * 1024 + 512);
        gld16(gB0l + kt, Bl[buf] + w * 1024);
        gld16(gB1l + kt, Bl[buf] + w * 1024 + 512);
    };
    auto loadA = [&](int kt) {
        AV v;
        v.c00 = *(const float4*)(cp0 + kt);
        v.c01 = *(const float4*)(cp0 + kt + 4);
        v.g00 = *(const float4*)(gp0 + kt);
        v.g01 = *(const float4*)(gp0 + kt + 4);
        v.e00 = *(const float4*)(gp0 + DD + kt);
        v.e01 = *(const float4*)(gp0 + DD + kt + 4);
        v.c10 = *(const float4*)(cp1 + kt);
        v.c11 = *(const float4*)(cp1 + kt + 4);
        v.g10 = *(const float4*)(gp1 + kt);
        v.g11 = *(const float4*)(gp1 + kt + 4);
        v.e10 = *(const float4*)(gp1 + DD + kt);
        v.e11 = *(const float4*)(gp1 + DD + kt + 4);
        return v;
    };
    auto writeA = [&](int buf, const AV& v) {
        float4 m00, m01, m10, m11;
        m00.x = v.g00.x * v.c00.x + v.e00.x; m00.y = v.g00.y * v.c00.y + v.e00.y;
        m00.z = v.g00.z * v.c00.z + v.e00.z; m00.w = v.g00.w * v.c00.w + v.e00.w;
        m01.x = v.g01.x * v.c01.x + v.e01.x; m01.y = v.g01.y * v.c01.y + v.e01.y;
        m01.z = v.g01.z * v.c01.z + v.e01.z; m01.w = v.g01.w * v.c01.w + v.e01.w;
        m10.x = v.g10.x * v.c10.x + v.e10.x; m10.y = v.g10.y * v.c10.y + v.e10.y;
        m10.z = v.g10.z * v.c10.z + v.e10.z; m10.w = v.g10.w * v.c10.w + v.e10.w;
        m11.x = v.g11.x * v.c11.x + v.e11.x; m11.y = v.g11.y * v.c11.y + v.e11.y;
        m11.z = v.g11.z * v.c11.z + v.e11.z; m11.w = v.g11.w * v.c11.w + v.e11.w;
        split8(m00, m01, Ah[buf] + pa0 * 8, Al[buf] + pa0 * 8);
        split8(m10, m11, Ah[buf] + pa1 * 8, Al[buf] + pa1 * 8);
    };
    auto compute = [&](int buf) {
        b8 ah[4], al[4], bh[4], bl[4];
#pragma unroll
        for (int i = 0; i < 4; ++i) {
            ah[i] = *(const b8*)(Ah[buf] + offA[i]);
            al[i] = *(const b8*)(Al[buf] + offA[i]);
            bh[i] = *(const b8*)(Bh[buf] + offB[i]);
            bl[i] = *(const b8*)(Bl[buf] + offB[i]);
        }
#pragma unroll
        for (int mi = 0; mi < 4; ++mi)
#pragma unroll
            for (int ni = 0; ni < 4; ++ni) {
                acc[mi][ni] = mfma(ah[mi], bh[ni], acc[mi][ni]);
                acc[mi][ni] = mfma(ah[mi], bl[ni], acc[mi][ni]);
                acc[mi][ni] = mfma(al[mi], bh[ni], acc[mi][ni]);
            }
    };

    // prologue: A floats first (older), then gld16s, then writes
    {
        AV v0 = loadA(0);
        AV v1 = loadA(32);
        stgB(0, 0);
        stgB(1, 32);
        writeA(0, v0);
        writeA(1, v1);
    }
    int cur = 0;
    for (int t = 0; t < 16; ++t) {
        if (t < 15) asm volatile("s_waitcnt vmcnt(4) lgkmcnt(0)" ::: "memory");
        else        asm volatile("s_waitcnt vmcnt(0) lgkmcnt(0)" ::: "memory");
        __builtin_amdgcn_s_barrier();
        asm volatile("" ::: "memory");
        compute(cur);
        asm volatile("" ::: "memory");
        __builtin_amdgcn_s_barrier();
        if (t < 14) {
            AV v = loadA((t + 2) * 32);   // floats issued before gld16s
            stgB(cur, (t + 2) * 32);
            writeA(cur, v);
        }
        cur ^= 1;
    }

    const float d0v = db[0];
#pragma unroll
    for (int mi = 0; mi < 4; ++mi)
#pragma unroll
        for (int q = 0; q < 4; ++q) {
            int f = f0 + wm * 64 + mi * 16 + laneK * 4 + q;
            if (f < FR) {
#pragma unroll
                for (int ni = 0; ni < 4; ++ni) {
                    int s = s0 + wn * 64 + ni * 16 + lane16;
                    if (s < KSZ) out[(size_t)f * KSZ + s] = acc[mi][ni][q] + d0v;
                }
            }
        }
}

// ---------------------------------------------------------------------------
extern "C" void kernel_launch(void* const* d_in, const int* in_sizes, int n_in,
                              void* d_out, int out_size, void* d_ws, size_t ws_size,
                              hipStream_t stream) {
    const float* wav    = (const float*)d_in[0];
    const float* enc_w  = (const float*)d_in[1];
    const float* enc_b  = (const float*)d_in[2];
    const float* cb     = (const float*)d_in[3];
    const float* lin_w  = (const float*)d_in[4];
    const float* lin_b  = (const float*)d_in[5];
    const float* film_w = (const float*)d_in[6];
    const float* film_b = (const float*)d_in[7];
    const float* dec_w  = (const float*)d_in[8];
    const float* dec_b  = (const float*)d_in[9];
    float* out = (float*)d_out;

    char* p = (char*)d_ws;
    u16* embh = (u16*)p;                 p += (size_t)FRP * DD * 2;
    u16* embl = (u16*)p;                 p += (size_t)FRP * DD * 2;
    u16* ewh  = (u16*)p;                 p += (size_t)DD * KSZ * 2;
    u16* ewl  = (u16*)p;                 p += (size_t)DD * KSZ * 2;
    u16* cbh  = (u16*)p;                 p += (size_t)CK * DD * 2;
    u16* cbl  = (u16*)p;                 p += (size_t)CK * DD * 2;
    u16* dwfh = (u16*)p;                 p += (size_t)384 * DD * 2;
    u16* dwfl = (u16*)p;                 p += (size_t)384 * DD * 2;
    float* cbn  = (float*)p;             p += CK * 4;
    float* tsum = (float*)p;             p += NB * DD * 4;
    float* cond = (float*)p;             p += NB * DD * 4;
    float* gbv  = (float*)p;             p += NB * 2 * DD * 4;
    float* pmin = (float*)p;             p += FR * 8 * 4;
    int*   pidx = (int*)p;               p += FR * 8 * 4;

    k_prep<<<dim3(417), 256, 0, stream>>>(enc_w, ewh, ewl, cb, cbh, cbl,
                                          dec_w, dwfh, dwfl, cbn, tsum);
    k_enc<<<dim3(256), 256, 0, stream>>>(wav, ewh, ewl, enc_b, embh, embl, tsum);
    k_cond<<<dim3(128), 256, 0, stream>>>(tsum, lin_w, lin_b, cond);
    k_film<<<dim3(256), 256, 0, stream>>>(cond, film_w, film_b, gbv);
    k_dist<<<dim3(512), 256, 0, stream>>>(embh, embl, cbh, cbl, cbn, pmin, pidx);
    k_dec<<<dim3(3, 63), 256, 0, stream>>>(pmin, pidx, cb, gbv, dwfh, dwfl, dec_b, out);
}

// Round 10
// 166.747 us; speedup vs baseline: 1.2562x; 1.0327x over previous
//
#include <hip/hip_runtime.h>

#define FR   8000
#define FRP  8192    // padded to 64*128 for XCD-chunked dist mapping
#define DD   512
#define CK   1024
#define KSZ  320
#define TT   500
#define NB   16

typedef unsigned int u32;
typedef unsigned short u16;
typedef __attribute__((ext_vector_type(8))) short b8;   // 8 x bf16 bits
typedef __attribute__((ext_vector_type(4))) float f4;

__device__ __forceinline__ float bf2f(u16 h) {
    u32 u = ((u32)h) << 16;
    return __builtin_bit_cast(float, u);
}
__device__ __forceinline__ u16 f2bf(float f) {  // RNE
    u32 u = __builtin_bit_cast(u32, f);
    u32 r = u + 0x7FFFu + ((u >> 16) & 1u);
    return (u16)(r >> 16);
}

__device__ __forceinline__ void gld16(const u16* g, u16* s) {
    __builtin_amdgcn_global_load_lds(
        (const __attribute__((address_space(1))) u32*)g,
        (__attribute__((address_space(3))) u32*)s, 16, 0, 0);
}

__device__ __forceinline__ f4 mfma(b8 a, b8 b, f4 c) {
    return __builtin_amdgcn_mfma_f32_16x16x32_bf16(a, b, c, 0, 0, 0);
}

__device__ __forceinline__ void split8(float4 a, float4 b, u16* dh, u16* dl) {
    float xs[8] = {a.x, a.y, a.z, a.w, b.x, b.y, b.z, b.w};
    union { u16 u[8]; b8 v; } H, L;
#pragma unroll
    for (int i = 0; i < 8; ++i) {
        u16 h = f2bf(xs[i]);
        H.u[i] = h;
        L.u[i] = f2bf(xs[i] - bf2f(h));
    }
    *(b8*)dh = H.v;
    *(b8*)dl = L.v;
}

// ---------------------------------------------------------------------------
// Merged prep (unchanged from R9):
//  [0,80) split enc_w | [80,336) split cb | [336,368) cbnorm
//  [368,416) dwf transpose | [416] zero tsum
// ---------------------------------------------------------------------------
__global__ __launch_bounds__(256) void k_prep(const float* __restrict__ enc_w,
                                              u16* __restrict__ ewh, u16* __restrict__ ewl,
                                              const float* __restrict__ cb,
                                              u16* __restrict__ cbh, u16* __restrict__ cbl,
                                              const float* __restrict__ dw,
                                              u16* __restrict__ dwfh, u16* __restrict__ dwfl,
                                              float* __restrict__ cbn,
                                              float* __restrict__ tsum) {
    const int bid = blockIdx.x, tid = threadIdx.x;
    if (bid < 80) {
        int i = (bid * 256 + tid) * 8;
        float4 a = *(const float4*)&enc_w[i];
        float4 b = *(const float4*)&enc_w[i + 4];
        split8(a, b, &ewh[i], &ewl[i]);
    } else if (bid < 336) {
        int i = ((bid - 80) * 256 + tid) * 8;
        float4 a = *(const float4*)&cb[i];
        float4 b = *(const float4*)&cb[i + 4];
        split8(a, b, &cbh[i], &cbl[i]);
    } else if (bid < 368) {
        int c = (bid - 336) * 32 + (tid >> 3);
        int l = tid & 7;
        float s = 0.f;
        for (int j = l * 4; j < DD; j += 32) {
            float4 v = *(const float4*)&cb[c * DD + j];
            s += v.x * v.x + v.y * v.y + v.z * v.z + v.w * v.w;
        }
        s += __shfl_xor(s, 1);
        s += __shfl_xor(s, 2);
        s += __shfl_xor(s, 4);
        if (l == 0) cbn[c] = s;
    } else if (bid < 416) {
        int bid2 = bid - 368;               // 48 blocks: 8 d x 6 s
        int d0 = (bid2 & 7) * 64;
        int sb = bid2 >> 3;
        int s0 = sb * 64;
        if (sb == 5) {                      // zero pad rows 320..383
            b8 z = {};
#pragma unroll
            for (int k = 0; k < 2; ++k) {
                int lin = tid * 2 + k;
                int row = 320 + (lin >> 3);
                int col = (lin & 7) * 8;
                *(b8*)&dwfh[(size_t)row * DD + d0 + col] = z;
                *(b8*)&dwfl[(size_t)row * DD + d0 + col] = z;
            }
            return;
        }
        __shared__ float t64[64][68];
        const int u0 = 256 - s0;
#pragma unroll
        for (int p = 0; p < 4; ++p) {
            int row = (tid >> 4) + 16 * p;
            int c4 = (tid & 15) * 4;
            float4 v = *(const float4*)&dw[(size_t)(d0 + row) * KSZ + u0 + c4];
            t64[row][c4] = v.x; t64[row][c4 + 1] = v.y;
            t64[row][c4 + 2] = v.z; t64[row][c4 + 3] = v.w;
        }
        __syncthreads();
        const int i = tid >> 2;
        const int jq = (tid & 3) * 16;
        union { u16 u[8]; b8 v; } H0, L0, H1, L1;
#pragma unroll
        for (int j = 0; j < 8; ++j) {
            float m = t64[jq + j][63 - i];
            u16 h = f2bf(m);
            H0.u[j] = h; L0.u[j] = f2bf(m - bf2f(h));
            float m2 = t64[jq + 8 + j][63 - i];
            u16 h2 = f2bf(m2);
            H1.u[j] = h2; L1.u[j] = f2bf(m2 - bf2f(h2));
        }
        size_t o = (size_t)(s0 + i) * DD + d0 + jq;
        *(b8*)&dwfh[o] = H0.v; *(b8*)&dwfh[o + 8] = H1.v;
        *(b8*)&dwfl[o] = L0.v; *(b8*)&dwfl[o + 8] = L1.v;
    } else {
        float4 z = {0.f, 0.f, 0.f, 0.f};
#pragma unroll
        for (int k = 0; k < 8; ++k)
            *(float4*)&tsum[(tid * 8 + k) * 4] = z;
    }
}

// ---------------------------------------------------------------------------
// Encoder: 512 threads, 8 waves (2 f-halves x 4 d-quarters), tile 128x128.
// A = wav fp32 reg-split (1 split8/thread); B = pre-split enc_w via gld16.
// Fused time-avg partials into epilogue.
// ---------------------------------------------------------------------------
__global__ __launch_bounds__(512, 4) void k_enc(const float* __restrict__ wav,
                                                const u16* __restrict__ Bhg,
                                                const u16* __restrict__ Blg,
                                                const float* __restrict__ eb,
                                                u16* __restrict__ embh,
                                                u16* __restrict__ embl,
                                                float* __restrict__ tsum) {
    __shared__ __align__(16) u16 Ah[2][4096], Al[2][4096], Bh[2][4096], Bl[2][4096];
    __shared__ float tred[2][128][2];
    const int tid = threadIdx.x;
    const int l = tid & 63, w = tid >> 6, wm = w >> 2, wn = w & 3;
    const int lane16 = l & 15, laneK = l >> 4;
    const int g = blockIdx.x;
    const int xcd = g & 7, slot = g >> 3;
    const int f0 = (xcd * 8 + (slot & 7)) * 128;
    const int d0 = (slot >> 3) * 128;

    // staging decode: 1 slot per thread (slot = tid, 512 slots of 16B)
    const int sr = tid >> 2;                       // row 0..127
    const int sq = (tid & 3) ^ ((sr >> 1) & 3);    // XOR-swizzled k-chunk
    int fa = f0 + sr; if (fa > FR - 1) fa = FR - 1;
    const float* wv = wav + (size_t)fa * KSZ + sq * 8;
    const u16* gBh = Bhg + (size_t)(d0 + sr) * KSZ + sq * 8;
    const u16* gBl = Blg + (size_t)(d0 + sr) * KSZ + sq * 8;

    int offA[4], offB[2];
#pragma unroll
    for (int i = 0; i < 4; ++i) {
        int ra = wm * 64 + i * 16 + lane16;
        offA[i] = (ra * 4 + (laneK ^ ((ra >> 1) & 3))) * 8;
    }
#pragma unroll
    for (int i = 0; i < 2; ++i) {
        int rb = wn * 32 + i * 16 + lane16;
        offB[i] = (rb * 4 + (laneK ^ ((rb >> 1) & 3))) * 8;
    }

    f4 zero = {0.f, 0.f, 0.f, 0.f};
    f4 acc[4][2];
#pragma unroll
    for (int i = 0; i < 4; ++i)
#pragma unroll
        for (int j = 0; j < 2; ++j) acc[i][j] = zero;

    struct AW { float4 x0, x1; };
    auto loadA = [&](int kt) {
        AW v;
        v.x0 = *(const float4*)(wv + kt);
        v.x1 = *(const float4*)(wv + kt + 4);
        return v;
    };
    auto writeA = [&](int buf, const AW& v) {
        split8(v.x0, v.x1, Ah[buf] + tid * 8, Al[buf] + tid * 8);
    };
    auto stgB = [&](int buf, int kt) {
        gld16(gBh + kt, Bh[buf] + w * 512);
        gld16(gBl + kt, Bl[buf] + w * 512);
    };
    auto compute = [&](int buf) {
        b8 ah[4], al[4], bh[2], bl[2];
#pragma unroll
        for (int i = 0; i < 4; ++i) {
            ah[i] = *(const b8*)(Ah[buf] + offA[i]);
            al[i] = *(const b8*)(Al[buf] + offA[i]);
        }
#pragma unroll
        for (int i = 0; i < 2; ++i) {
            bh[i] = *(const b8*)(Bh[buf] + offB[i]);
            bl[i] = *(const b8*)(Bl[buf] + offB[i]);
        }
        __builtin_amdgcn_s_setprio(1);
#pragma unroll
        for (int mi = 0; mi < 4; ++mi)
#pragma unroll
            for (int ni = 0; ni < 2; ++ni) {
                acc[mi][ni] = mfma(ah[mi], bh[ni], acc[mi][ni]);
                acc[mi][ni] = mfma(ah[mi], bl[ni], acc[mi][ni]);
                acc[mi][ni] = mfma(al[mi], bh[ni], acc[mi][ni]);
            }
        __builtin_amdgcn_s_setprio(0);
    };

    {
        AW v0 = loadA(0);
        AW v1 = loadA(32);
        stgB(0, 0);
        stgB(1, 32);
        writeA(0, v0);
        writeA(1, v1);
    }
    int cur = 0;
    for (int t = 0; t < 10; ++t) {
        if (t < 9) asm volatile("s_waitcnt vmcnt(2) lgkmcnt(0)" ::: "memory");
        else       asm volatile("s_waitcnt vmcnt(0) lgkmcnt(0)" ::: "memory");
        __builtin_amdgcn_s_barrier();
        asm volatile("" ::: "memory");
        compute(cur);
        asm volatile("" ::: "memory");
        __builtin_amdgcn_s_barrier();
        if (t < 8) {
            AW v = loadA((t + 2) * 32);
            stgB(cur, (t + 2) * 32);
            writeA(cur, v);
        }
        cur ^= 1;
    }

    float ebv[2];
#pragma unroll
    for (int ni = 0; ni < 2; ++ni) ebv[ni] = eb[d0 + wn * 32 + ni * 16 + lane16];

    const int bA = f0 / TT;
    const int fB = min((bA + 1) * TT, f0 + 128);
    float sumA[2] = {}, sumB[2] = {};
#pragma unroll
    for (int mi = 0; mi < 4; ++mi)
#pragma unroll
        for (int q = 0; q < 4; ++q) {
            int f = f0 + wm * 64 + mi * 16 + laneK * 4 + q;
            bool live = f < FR;
            bool sideA = f < fB;
#pragma unroll
            for (int ni = 0; ni < 2; ++ni) {
                int d = d0 + wn * 32 + ni * 16 + lane16;
                float v = acc[mi][ni][q] + ebv[ni];
                u16 h = f2bf(v);
                size_t o = (size_t)f * DD + d;
                embh[o] = h;
                embl[o] = f2bf(v - bf2f(h));
                if (live) { if (sideA) sumA[ni] += v; else sumB[ni] += v; }
            }
        }
#pragma unroll
    for (int m = 16; m <= 32; m <<= 1)
#pragma unroll
        for (int ni = 0; ni < 2; ++ni) {
            sumA[ni] += __shfl_xor(sumA[ni], m);
            sumB[ni] += __shfl_xor(sumB[ni], m);
        }
    if (laneK == 0)
#pragma unroll
        for (int ni = 0; ni < 2; ++ni) {
            tred[wm][wn * 32 + ni * 16 + lane16][0] = sumA[ni];
            tred[wm][wn * 32 + ni * 16 + lane16][1] = sumB[ni];
        }
    __syncthreads();
    if (tid < 128 && bA < NB) {
        float a = tred[0][tid][0] + tred[1][tid][0];
        int d = d0 + tid;
        atomicAdd(&tsum[bA * DD + d], a);
        if (fB < f0 + 128 && bA + 1 < NB) {
            float b = tred[0][tid][1] + tred[1][tid][1];
            atomicAdd(&tsum[(bA + 1) * DD + d], b);
        }
    }
}

// ---------------------------------------------------------------------------
// cond / film (unchanged)
// ---------------------------------------------------------------------------
__global__ __launch_bounds__(256) void k_cond(const float* __restrict__ tsum,
                                              const float* __restrict__ lw,
                                              const float* __restrict__ lb,
                                              float* __restrict__ cond) {
    __shared__ float stv[NB * DD];
    const float inv = 1.0f / TT;
    for (int i = threadIdx.x * 4; i < NB * DD; i += 1024) {
        float4 v = *(const float4*)&tsum[i];
        v.x *= inv; v.y *= inv; v.z *= inv; v.w *= inv;
        *(float4*)&stv[i] = v;
    }
    __syncthreads();
    const int w = threadIdx.x >> 6, lane = threadIdx.x & 63;
    const int row = blockIdx.x * 4 + w;
    float wv[8];
#pragma unroll
    for (int j = 0; j < 8; ++j) wv[j] = lw[(size_t)row * DD + lane + 64 * j];
    float r[NB];
#pragma unroll
    for (int b = 0; b < NB; ++b) {
        float s = 0.f;
#pragma unroll
        for (int j = 0; j < 8; ++j) s += wv[j] * stv[b * DD + lane + 64 * j];
        r[b] = s;
    }
#pragma unroll
    for (int m = 32; m >= 1; m >>= 1)
#pragma unroll
        for (int b = 0; b < NB; ++b) r[b] += __shfl_xor(r[b], m);
    if (lane < NB) cond[lane * DD + row] = r[lane] + lb[row];
}

__global__ __launch_bounds__(256) void k_film(const float* __restrict__ cond,
                                              const float* __restrict__ fw,
                                              const float* __restrict__ fb,
                                              float* __restrict__ gbv) {
    __shared__ float sc[NB * DD];
    for (int i = threadIdx.x * 4; i < NB * DD; i += 1024)
        *(float4*)&sc[i] = *(const float4*)&cond[i];
    __syncthreads();
    const int w = threadIdx.x >> 6, lane = threadIdx.x & 63;
    const int row = blockIdx.x * 4 + w;
    float wv[8];
#pragma unroll
    for (int j = 0; j < 8; ++j) wv[j] = fw[(size_t)row * DD + lane + 64 * j];
    float r[NB];
#pragma unroll
    for (int b = 0; b < NB; ++b) {
        float s = 0.f;
#pragma unroll
        for (int j = 0; j < 8; ++j) s += wv[j] * sc[b * DD + lane + 64 * j];
        r[b] = s;
    }
#pragma unroll
    for (int m = 32; m >= 1; m >>= 1)
#pragma unroll
        for (int b = 0; b < NB; ++b) r[b] += __shfl_xor(r[b], m);
    if (lane < NB) gbv[lane * 2 * DD + row] = r[lane] + fb[row];
}

// ---------------------------------------------------------------------------
// VQ dist: 512 threads, 8 waves (2 f-halves x 4 c-quarters), tile 128x128.
// Grid 512 (XCD-chunked, unchanged mapping). 16 waves/CU.
// ---------------------------------------------------------------------------
__global__ __launch_bounds__(512, 4) void k_dist(const u16* __restrict__ Ahg,
                                                 const u16* __restrict__ Alg,
                                                 const u16* __restrict__ Bhg,
                                                 const u16* __restrict__ Blg,
                                                 const float* __restrict__ cbn,
                                                 float* __restrict__ pmin,
                                                 int* __restrict__ pidx) {
    __shared__ __align__(16) u16 Ah[2][4096], Al[2][4096], Bh[2][4096], Bl[2][4096];
    __shared__ float s_best[128][4];
    __shared__ int s_bidx[128][4];
    const int tid = threadIdx.x;
    const int l = tid & 63, w = tid >> 6, wm = w >> 2, wn = w & 3;
    const int lane16 = l & 15, laneK = l >> 4;
    const int g = blockIdx.x;
    const int xcd = g & 7, slot = g >> 3;
    const int fbase = (xcd * 8 + (slot & 7)) * 128;
    const int cy = slot >> 3;
    const int c0 = cy * 128;

    // staging decode: 1 slot per thread per array
    const int sr = tid >> 2;
    const int sq = (tid & 3) ^ ((sr >> 1) & 3);
    const u16* gAh = Ahg + (size_t)(fbase + sr) * DD + sq * 8;
    const u16* gAl = Alg + (size_t)(fbase + sr) * DD + sq * 8;
    const u16* gBh = Bhg + (size_t)(c0 + sr) * DD + sq * 8;
    const u16* gBl = Blg + (size_t)(c0 + sr) * DD + sq * 8;

    int offA[4], offB[2];
#pragma unroll
    for (int i = 0; i < 4; ++i) {
        int ra = wm * 64 + i * 16 + lane16;
        offA[i] = (ra * 4 + (laneK ^ ((ra >> 1) & 3))) * 8;
    }
#pragma unroll
    for (int i = 0; i < 2; ++i) {
        int rb = wn * 32 + i * 16 + lane16;
        offB[i] = (rb * 4 + (laneK ^ ((rb >> 1) & 3))) * 8;
    }

    f4 zero = {0.f, 0.f, 0.f, 0.f};
    f4 acc[4][2];
#pragma unroll
    for (int i = 0; i < 4; ++i)
#pragma unroll
        for (int j = 0; j < 2; ++j) acc[i][j] = zero;

    auto stg = [&](int buf, int kt) {
        gld16(gAh + kt, Ah[buf] + w * 512);
        gld16(gAl + kt, Al[buf] + w * 512);
        gld16(gBh + kt, Bh[buf] + w * 512);
        gld16(gBl + kt, Bl[buf] + w * 512);
    };
    auto compute = [&](int buf) {
        b8 ah[4], al[4], bh[2], bl[2];
#pragma unroll
        for (int i = 0; i < 4; ++i) {
            ah[i] = *(const b8*)(Ah[buf] + offA[i]);
            al[i] = *(const b8*)(Al[buf] + offA[i]);
        }
#pragma unroll
        for (int i = 0; i < 2; ++i) {
            bh[i] = *(const b8*)(Bh[buf] + offB[i]);
            bl[i] = *(const b8*)(Bl[buf] + offB[i]);
        }
        __builtin_amdgcn_s_setprio(1);
#pragma unroll
        for (int mi = 0; mi < 4; ++mi)
#pragma unroll
            for (int ni = 0; ni < 2; ++ni) {
                acc[mi][ni] = mfma(ah[mi], bh[ni], acc[mi][ni]);
                acc[mi][ni] = mfma(ah[mi], bl[ni], acc[mi][ni]);
                acc[mi][ni] = mfma(al[mi], bh[ni], acc[mi][ni]);
            }
        __builtin_amdgcn_s_setprio(0);
    };

    stg(0, 0);
    stg(1, 32);
    int cur = 0;
    for (int t = 0; t < 16; ++t) {
        if (t < 15) asm volatile("s_waitcnt vmcnt(4)" ::: "memory");
        else        asm volatile("s_waitcnt vmcnt(0)" ::: "memory");
        __builtin_amdgcn_s_barrier();
        asm volatile("" ::: "memory");
        compute(cur);
        asm volatile("" ::: "memory");
        __builtin_amdgcn_s_barrier();
        if (t < 14) stg(cur, (t + 2) * 32);
        cur ^= 1;
    }

    float cbv[2];
    int cidx[2];
#pragma unroll
    for (int ni = 0; ni < 2; ++ni) {
        cidx[ni] = c0 + wn * 32 + ni * 16 + lane16;
        cbv[ni] = cbn[cidx[ni]];
    }
#pragma unroll
    for (int mi = 0; mi < 4; ++mi)
#pragma unroll
        for (int q = 0; q < 4; ++q) {
            float best = 3.4e38f;
            int bi = 0x7fffffff;
#pragma unroll
            for (int ni = 0; ni < 2; ++ni) {
                float s = cbv[ni] - 2.0f * acc[mi][ni][q];
                if (s < best || (s == best && cidx[ni] < bi)) { best = s; bi = cidx[ni]; }
            }
#pragma unroll
            for (int m = 8; m >= 1; m >>= 1) {
                float os = __shfl_xor(best, m);
                int oi = __shfl_xor(bi, m);
                if (os < best || (os == best && oi < bi)) { best = os; bi = oi; }
            }
            if (lane16 == 0) {
                int rl = wm * 64 + mi * 16 + laneK * 4 + q;
                s_best[rl][wn] = best;
                s_bidx[rl][wn] = bi;
            }
        }
    __syncthreads();
    if (tid < 128) {
        float best = s_best[tid][0];
        int bi = s_bidx[tid][0];
#pragma unroll
        for (int y = 1; y < 4; ++y) {
            float s = s_best[tid][y];
            int ii = s_bidx[tid][y];
            if (s < best || (s == best && ii < bi)) { best = s; bi = ii; }
        }
        int f = fbase + tid;
        if (f < FR) {
            pmin[f * 8 + cy] = best;
            pidx[f * 8 + cy] = bi;
        }
    }
}

// ---------------------------------------------------------------------------
// Decoder: tile 64f x 64s, grid (5, 125) = 625 blocks (~2.4/CU, LDS 33KB ->
// 4 blocks/CU cap). FR = 125*64 exactly, KSZ = 5*64 exactly: no bounds checks.
// Fused combine + gather + FiLM + split in A-staging (reg -> ds_write).
// ---------------------------------------------------------------------------
__global__ __launch_bounds__(256, 4) void k_dec(const float* __restrict__ pmin,
                                                const int* __restrict__ pidx,
                                                const float* __restrict__ cb,
                                                const float* __restrict__ gbv,
                                                const u16* __restrict__ Bhg,
                                                const u16* __restrict__ Blg,
                                                const float* __restrict__ db,
                                                float* __restrict__ out) {
    __shared__ __align__(16) u16 Ah[2][2048], Al[2][2048], Bh[2][2048], Bl[2][2048];
    __shared__ int codes_lds[64];
    __shared__ int b_lds[64];
    const int tid = threadIdx.x;
    const int l = tid & 63, w = tid >> 6, wm = w >> 1, wn = w & 1;
    const int lane16 = l & 15, laneK = l >> 4;
    const int f0 = blockIdx.y * 64, s0 = blockIdx.x * 64;

    if (tid < 64) {
        int fc = f0 + tid;
        float best = pmin[fc * 8];
        int bi = pidx[fc * 8];
#pragma unroll
        for (int y = 1; y < 8; ++y) {
            float s = pmin[fc * 8 + y];
            if (s < best) { best = s; bi = pidx[fc * 8 + y]; }
        }
        codes_lds[tid] = bi;
        b_lds[tid] = fc / TT;
    }
    __syncthreads();

    // staging decode: 1 slot/thread (slot = tid, 256 slots of 16B)
    const int sr = tid >> 2;                       // row 0..63
    const int sq = (tid & 3) ^ ((sr >> 1) & 3);
    const float* cp = cb + (size_t)codes_lds[sr] * DD + sq * 8;
    const float* gp = gbv + b_lds[sr] * 2 * DD + sq * 8;
    const float* ep = gp + DD;
    const u16* gBh = Bhg + (size_t)(s0 + sr) * DD + sq * 8;
    const u16* gBl = Blg + (size_t)(s0 + sr) * DD + sq * 8;

    int offA[2], offB[2];
#pragma unroll
    for (int i = 0; i < 2; ++i) {
        int ra = wm * 32 + i * 16 + lane16;
        offA[i] = (ra * 4 + (laneK ^ ((ra >> 1) & 3))) * 8;
        int rb = wn * 32 + i * 16 + lane16;
        offB[i] = (rb * 4 + (laneK ^ ((rb >> 1) & 3))) * 8;
    }

    f4 zero = {0.f, 0.f, 0.f, 0.f};
    f4 acc[2][2];
#pragma unroll
    for (int i = 0; i < 2; ++i)
#pragma unroll
        for (int j = 0; j < 2; ++j) acc[i][j] = zero;

    struct AV { float4 c0, c1, g0, g1, e0, e1; };
    auto loadA = [&](int kt) {
        AV v;
        v.c0 = *(const float4*)(cp + kt);
        v.c1 = *(const float4*)(cp + kt + 4);
        v.g0 = *(const float4*)(gp + kt);
        v.g1 = *(const float4*)(gp + kt + 4);
        v.e0 = *(const float4*)(ep + kt);
        v.e1 = *(const float4*)(ep + kt + 4);
        return v;
    };
    auto writeA = [&](int buf, const AV& v) {
        float4 m0, m1;
        m0.x = v.g0.x * v.c0.x + v.e0.x; m0.y = v.g0.y * v.c0.y + v.e0.y;
        m0.z = v.g0.z * v.c0.z + v.e0.z; m0.w = v.g0.w * v.c0.w + v.e0.w;
        m1.x = v.g1.x * v.c1.x + v.e1.x; m1.y = v.g1.y * v.c1.y + v.e1.y;
        m1.z = v.g1.z * v.c1.z + v.e1.z; m1.w = v.g1.w * v.c1.w + v.e1.w;
        split8(m0, m1, Ah[buf] + tid * 8, Al[buf] + tid * 8);
    };
    auto stgB = [&](int buf, int kt) {
        gld16(gBh + kt, Bh[buf] + w * 512);
        gld16(gBl + kt, Bl[buf] + w * 512);
    };
    auto compute = [&](int buf) {
        b8 ah[2], al[2], bh[2], bl[2];
#pragma unroll
        for (int i = 0; i < 2; ++i) {
            ah[i] = *(const b8*)(Ah[buf] + offA[i]);
            al[i] = *(const b8*)(Al[buf] + offA[i]);
            bh[i] = *(const b8*)(Bh[buf] + offB[i]);
            bl[i] = *(const b8*)(Bl[buf] + offB[i]);
        }
        __builtin_amdgcn_s_setprio(1);
#pragma unroll
        for (int mi = 0; mi < 2; ++mi)
#pragma unroll
            for (int ni = 0; ni < 2; ++ni) {
                acc[mi][ni] = mfma(ah[mi], bh[ni], acc[mi][ni]);
                acc[mi][ni] = mfma(ah[mi], bl[ni], acc[mi][ni]);
                acc[mi][ni] = mfma(al[mi], bh[ni], acc[mi][ni]);
            }
        __builtin_amdgcn_s_setprio(0);
    };

    {
        AV v0 = loadA(0);
        AV v1 = loadA(32);
        stgB(0, 0);
        stgB(1, 32);
        writeA(0, v0);
        writeA(1, v1);
    }
    int cur = 0;
    for (int t = 0; t < 16; ++t) {
        if (t < 15) asm volatile("s_waitcnt vmcnt(2) lgkmcnt(0)" ::: "memory");
        else        asm volatile("s_waitcnt vmcnt(0) lgkmcnt(0)" ::: "memory");
        __builtin_amdgcn_s_barrier();
        asm volatile("" ::: "memory");
        compute(cur);
        asm volatile("" ::: "memory");
        __builtin_amdgcn_s_barrier();
        if (t < 14) {
            AV v = loadA((t + 2) * 32);
            stgB(cur, (t + 2) * 32);
            writeA(cur, v);
        }
        cur ^= 1;
    }

    const float d0v = db[0];
#pragma unroll
    for (int mi = 0; mi < 2; ++mi)
#pragma unroll
        for (int q = 0; q < 4; ++q) {
            int f = f0 + wm * 32 + mi * 16 + laneK * 4 + q;
#pragma unroll
            for (int ni = 0; ni < 2; ++ni) {
                int s = s0 + wn * 32 + ni * 16 + lane16;
                out[(size_t)f * KSZ + s] = acc[mi][ni][q] + d0v;
            }
        }
}

// ---------------------------------------------------------------------------
extern "C" void kernel_launch(void* const* d_in, const int* in_sizes, int n_in,
                              void* d_out, int out_size, void* d_ws, size_t ws_size,
                              hipStream_t stream) {
    const float* wav    = (const float*)d_in[0];
    const float* enc_w  = (const float*)d_in[1];
    const float* enc_b  = (const float*)d_in[2];
    const float* cb     = (const float*)d_in[3];
    const float* lin_w  = (const float*)d_in[4];
    const float* lin_b  = (const float*)d_in[5];
    const float* film_w = (const float*)d_in[6];
    const float* film_b = (const float*)d_in[7];
    const float* dec_w  = (const float*)d_in[8];
    const float* dec_b  = (const float*)d_in[9];
    float* out = (float*)d_out;

    char* p = (char*)d_ws;
    u16* embh = (u16*)p;                 p += (size_t)FRP * DD * 2;
    u16* embl = (u16*)p;                 p += (size_t)FRP * DD * 2;
    u16* ewh  = (u16*)p;                 p += (size_t)DD * KSZ * 2;
    u16* ewl  = (u16*)p;                 p += (size_t)DD * KSZ * 2;
    u16* cbh  = (u16*)p;                 p += (size_t)CK * DD * 2;
    u16* cbl  = (u16*)p;                 p += (size_t)CK * DD * 2;
    u16* dwfh = (u16*)p;                 p += (size_t)384 * DD * 2;
    u16* dwfl = (u16*)p;                 p += (size_t)384 * DD * 2;
    float* cbn  = (float*)p;             p += CK * 4;
    float* tsum = (float*)p;             p += NB * DD * 4;
    float* cond = (float*)p;             p += NB * DD * 4;
    float* gbv  = (float*)p;             p += NB * 2 * DD * 4;
    float* pmin = (float*)p;             p += FR * 8 * 4;
    int*   pidx = (int*)p;               p += FR * 8 * 4;

    k_prep<<<dim3(417), 256, 0, stream>>>(enc_w, ewh, ewl, cb, cbh, cbl,
                                          dec_w, dwfh, dwfl, cbn, tsum);
    k_enc<<<dim3(256), 512, 0, stream>>>(wav, ewh, ewl, enc_b, embh, embl, tsum);
    k_dist<<<dim3(512), 512, 0, stream>>>(embh, embl, cbh, cbl, cbn, pmin, pidx);
    k_cond<<<dim3(128), 256, 0, stream>>>(tsum, lin_w, lin_b, cond);
    k_film<<<dim3(256), 256, 0, stream>>>(cond, film_w, film_b, gbv);
    k_dec<<<dim3(5, 125), 256, 0, stream>>>(pmin, pidx, cb, gbv, dwfh, dwfl, dec_b, out);
}